// Round 4
// baseline (7012.692 us; speedup 1.0000x reference)
//
#include <hip/hip_runtime.h>
#include <hip/hip_fp16.h>
#include <math.h>

#define B_  64
#define S_  512
#define E_  300
#define H_  256
#define G4_ 1024
#define T_  22
#define M_  (B_*S_)
#define C_  16              // LSTM time chunk
#define NCH (S_/C_)         // 32 chunks
#define CROWS (B_*C_)       // 1024 rows per chunk per dir
#define START_ (T_-2)
#define STOP_  (T_-1)

__device__ __forceinline__ float sigf(float x){ return 1.f/(1.f+expf(-x)); }

// w_hh [1024,256] -> wT16 [256][1024] (fp16) with wT[k][4*j+g] = w_hh[g*256+j][k]
__global__ __launch_bounds__(256) void wtr_kernel(const float* __restrict__ whh, __half* __restrict__ wT){
  int tid = blockIdx.x*256 + threadIdx.x;
  if (tid >= H_*G4_) return;
  int k = tid >> 10;
  int r = tid & 1023;
  int j = r >> 2, gi = r & 3;
  wT[tid] = __float2half(whh[(size_t)(gi*H_ + j)*H_ + k]);
}

// 64x64 tile GEMM body: C[row0:+64, col0:+64] = A @ W^T + bias
// gather mode: local row r -> word/mask flat index (r/chunkC)*S_ + t0 + (r%chunkC)
__device__ __forceinline__ void gemm_tile_body(
    const float* __restrict__ A,
    const int* __restrict__ word, const int* __restrict__ maskp, const float* __restrict__ emb,
    const float* __restrict__ W, const float* __restrict__ bias,
    float* __restrict__ C, int K, int N, int gather, int t0, int chunkC,
    int row0, int col0) {
  __shared__ __align__(16) float As[16][68];
  __shared__ __align__(16) float Bs[16][68];
  __shared__ int   widx[64];
  __shared__ float wmsk[64];
  const int tid = threadIdx.x;
  const int tn = tid & 15, tm = tid >> 4;
  if (gather) {
    if (tid < 64) {
      int r  = row0 + tid;
      int b  = r / chunkC;
      int tl = r % chunkC;
      int wr = b*S_ + t0 + tl;
      widx[tid] = word[wr];
      wmsk[tid] = (float)maskp[wr];
    }
    __syncthreads();
  }
  float acc[4][4];
  #pragma unroll
  for (int i=0;i<4;i++)
    #pragma unroll
    for (int j=0;j<4;j++) acc[i][j]=0.f;

  for (int k0 = 0; k0 < K; k0 += 16) {
    #pragma unroll
    for (int i = 0; i < 4; ++i) {
      const int li = tid + (i<<8);
      const int m  = li >> 4, kk = li & 15;
      const int kg = k0 + kk;
      float av = 0.f;
      if (kg < K) {
        if (gather) av = emb[(size_t)widx[m]*K + kg] * wmsk[m];
        else        av = A[(size_t)(row0+m)*K + kg];
      }
      As[kk][m] = av;
      const int nc = col0 + m;
      Bs[kk][m] = (kg < K && nc < N) ? W[(size_t)nc*K + kg] : 0.f;
    }
    __syncthreads();
    #pragma unroll
    for (int kk = 0; kk < 16; ++kk) {
      const float4 a = *(const float4*)&As[kk][tm<<2];
      const float4 b = *(const float4*)&Bs[kk][tn<<2];
      acc[0][0]=fmaf(a.x,b.x,acc[0][0]); acc[0][1]=fmaf(a.x,b.y,acc[0][1]);
      acc[0][2]=fmaf(a.x,b.z,acc[0][2]); acc[0][3]=fmaf(a.x,b.w,acc[0][3]);
      acc[1][0]=fmaf(a.y,b.x,acc[1][0]); acc[1][1]=fmaf(a.y,b.y,acc[1][1]);
      acc[1][2]=fmaf(a.y,b.z,acc[1][2]); acc[1][3]=fmaf(a.y,b.w,acc[1][3]);
      acc[2][0]=fmaf(a.z,b.x,acc[2][0]); acc[2][1]=fmaf(a.z,b.y,acc[2][1]);
      acc[2][2]=fmaf(a.z,b.z,acc[2][2]); acc[2][3]=fmaf(a.z,b.w,acc[2][3]);
      acc[3][0]=fmaf(a.w,b.x,acc[3][0]); acc[3][1]=fmaf(a.w,b.y,acc[3][1]);
      acc[3][2]=fmaf(a.w,b.z,acc[3][2]); acc[3][3]=fmaf(a.w,b.w,acc[3][3]);
    }
    __syncthreads();
  }
  #pragma unroll
  for (int i=0;i<4;i++){
    const int r = row0 + (tm<<2) + i;
    #pragma unroll
    for (int j=0;j<4;j++){
      const int c = col0 + (tn<<2) + j;
      if (c < N) C[(size_t)r*N + c] = acc[i][j] + bias[c];
    }
  }
}

__global__ __launch_bounds__(256) void gemm_tiled(
    const float* __restrict__ A,
    const int* __restrict__ word, const int* __restrict__ maskp, const float* __restrict__ emb,
    const float* __restrict__ W, const float* __restrict__ bias,
    float* __restrict__ C, int K, int N, int gather, int t0, int chunkC) {
  gemm_tile_body(A, word, maskp, emb, W, bias, C, K, N, gather, t0, chunkC,
                 blockIdx.x << 6, blockIdx.y << 6);
}

// Fused launch: blocks [0,64) run the recurrence (2 batch x 1 dir each, fp16 weights);
// blocks [64, 64+512) compute next chunk's input-projection gates into gnext.
__global__ __launch_bounds__(256) void lstm_fused(
    const float* __restrict__ gcur, float* __restrict__ gnext,
    const int* __restrict__ word, const int* __restrict__ maskp, const float* __restrict__ emb,
    const float* __restrict__ w_ih_f, const float* __restrict__ b_f,
    const float* __restrict__ w_ih_b, const float* __restrict__ b_b,
    const __half* __restrict__ wTf, const __half* __restrict__ wTb,
    float* __restrict__ h_bi, float* __restrict__ stH, float* __restrict__ stC,
    int t0f, int t0b, int n0f, int n0b, int first) {
  const int bid = blockIdx.x;
  if (bid >= 64) {
    const int g2 = bid - 64;
    const int dir = g2 >> 8;
    const int tt = g2 & 255;
    const int rowt = tt & 15, colt = tt >> 4;
    const float* W  = dir ? w_ih_b : w_ih_f;
    const float* bs = dir ? b_b : b_f;
    float* Cout = gnext + (size_t)dir * CROWS * G4_;
    const int t0 = dir ? n0b : n0f;
    gemm_tile_body(nullptr, word, maskp, emb, W, bs, Cout, E_, G4_, 1, t0, C_,
                   rowt << 6, colt << 6);
    return;
  }
  // ---- recurrence role ----
  const int dir = bid & 1;
  const float* __restrict__ g  = gcur + (size_t)dir * CROWS * G4_;
  const __half* __restrict__ wT = dir ? wTb : wTf;
  const int b0 = (bid >> 1) * 2;
  const int tid = threadIdx.x;
  const int hoff = dir ? H_ : 0;
  __shared__ float hp[H_][2];
  float c0, c1;
  if (first) {
    hp[tid][0] = 0.f; hp[tid][1] = 0.f; c0 = 0.f; c1 = 0.f;
  } else {
    hp[tid][0] = stH[((size_t)(dir*B_ + b0))*H_ + tid];
    hp[tid][1] = stH[((size_t)(dir*B_ + b0 + 1))*H_ + tid];
    c0 = stC[((size_t)(dir*B_ + b0))*H_ + tid];
    c1 = stC[((size_t)(dir*B_ + b0 + 1))*H_ + tid];
  }
  __syncthreads();
  for (int sl = 0; sl < C_; ++sl) {
    const int t  = dir ? (t0b + C_ - 1 - sl) : (t0f + sl);
    const int tl = dir ? (C_ - 1 - sl) : sl;
    float ai0=0.f,af0=0.f,ag0=0.f,ao0=0.f, ai1=0.f,af1=0.f,ag1=0.f,ao1=0.f;
    #pragma unroll 8
    for (int k = 0; k < H_; ++k) {
      const uint2 u = *(const uint2*)(wT + ((k<<10) + (tid<<2)));
      __half2 p01, p23;
      *reinterpret_cast<unsigned int*>(&p01) = u.x;
      *reinterpret_cast<unsigned int*>(&p23) = u.y;
      const float2 f01 = __half22float2(p01);
      const float2 f23 = __half22float2(p23);
      const float h0 = hp[k][0], h1 = hp[k][1];
      ai0 = fmaf(f01.x, h0, ai0); af0 = fmaf(f01.y, h0, af0);
      ag0 = fmaf(f23.x, h0, ag0); ao0 = fmaf(f23.y, h0, ao0);
      ai1 = fmaf(f01.x, h1, ai1); af1 = fmaf(f01.y, h1, af1);
      ag1 = fmaf(f23.x, h1, ag1); ao1 = fmaf(f23.y, h1, ao1);
    }
    const size_t r0 = ((size_t)(b0*C_ + tl)) << 10;
    const size_t r1 = ((size_t)((b0+1)*C_ + tl)) << 10;
    float i0 = sigf(g[r0 + tid] + ai0);
    float f0 = sigf(g[r0 + H_ + tid] + af0);
    float z0 = tanhf(g[r0 + 2*H_ + tid] + ag0);
    float o0 = sigf(g[r0 + 3*H_ + tid] + ao0);
    c0 = f0*c0 + i0*z0;
    const float hn0 = o0 * tanhf(c0);
    float i1 = sigf(g[r1 + tid] + ai1);
    float f1 = sigf(g[r1 + H_ + tid] + af1);
    float z1 = tanhf(g[r1 + 2*H_ + tid] + ag1);
    float o1 = sigf(g[r1 + 3*H_ + tid] + ao1);
    c1 = f1*c1 + i1*z1;
    const float hn1 = o1 * tanhf(c1);
    __syncthreads();
    hp[tid][0] = hn0; hp[tid][1] = hn1;
    h_bi[((size_t)(b0*S_ + t))*(2*H_) + hoff + tid] = hn0;
    h_bi[((size_t)((b0+1)*S_ + t))*(2*H_) + hoff + tid] = hn1;
    __syncthreads();
  }
  stH[((size_t)(dir*B_ + b0))*H_ + tid]     = hp[tid][0];
  stH[((size_t)(dir*B_ + b0 + 1))*H_ + tid] = hp[tid][1];
  stC[((size_t)(dir*B_ + b0))*H_ + tid]     = c0;
  stC[((size_t)(dir*B_ + b0 + 1))*H_ + tid] = c1;
}

// Fused highway: block owns 64 rows of h [M,512]; caches A^T in LDS (139KB);
// loops 8 column-pair tiles (nl col c, gate col 512+c); writes h2 IN PLACE.
__global__ __launch_bounds__(256, 1) void gemm_hw(
    float* __restrict__ h, const float* __restrict__ hwW, const float* __restrict__ hwb) {
  __shared__ __align__(16) float At[512][68];   // At[k][r] = h[row0+r][k]
  __shared__ __align__(16) float Bn[16][68];
  __shared__ __align__(16) float Bg[16][68];
  const int tid = threadIdx.x;
  const int tn = tid & 15, tm = tid >> 4;
  const int row0 = blockIdx.x << 6;
  // load + transpose A tile: 8192 float4s over 256 threads
  for (int it = 0; it < 32; ++it) {
    const int idx = tid + (it << 8);      // float4 index
    const int r = idx >> 7;               // row 0..63
    const int c4 = (idx & 127) << 2;      // col 0..508
    const float4 v = *(const float4*)&h[(size_t)(row0 + r)*512 + c4];
    At[c4+0][r] = v.x; At[c4+1][r] = v.y; At[c4+2][r] = v.z; At[c4+3][r] = v.w;
  }
  __syncthreads();
  for (int cp = 0; cp < 8; ++cp) {
    const int col0 = cp << 6;
    float an[4][4], ag2[4][4];
    #pragma unroll
    for (int i=0;i<4;i++)
      #pragma unroll
      for (int j=0;j<4;j++){ an[i][j]=0.f; ag2[i][j]=0.f; }
    for (int k0 = 0; k0 < 512; k0 += 16) {
      #pragma unroll
      for (int i = 0; i < 4; ++i) {
        const int li = tid + (i<<8);
        const int m = li >> 4, kk = li & 15;
        Bn[kk][m] = hwW[(size_t)(col0 + m)*512 + k0 + kk];
        Bg[kk][m] = hwW[(size_t)(512 + col0 + m)*512 + k0 + kk];
      }
      __syncthreads();
      #pragma unroll
      for (int kk = 0; kk < 16; ++kk) {
        const float4 a  = *(const float4*)&At[k0+kk][tm<<2];
        const float4 bn = *(const float4*)&Bn[kk][tn<<2];
        const float4 bg = *(const float4*)&Bg[kk][tn<<2];
        an[0][0]=fmaf(a.x,bn.x,an[0][0]); an[0][1]=fmaf(a.x,bn.y,an[0][1]);
        an[0][2]=fmaf(a.x,bn.z,an[0][2]); an[0][3]=fmaf(a.x,bn.w,an[0][3]);
        an[1][0]=fmaf(a.y,bn.x,an[1][0]); an[1][1]=fmaf(a.y,bn.y,an[1][1]);
        an[1][2]=fmaf(a.y,bn.z,an[1][2]); an[1][3]=fmaf(a.y,bn.w,an[1][3]);
        an[2][0]=fmaf(a.z,bn.x,an[2][0]); an[2][1]=fmaf(a.z,bn.y,an[2][1]);
        an[2][2]=fmaf(a.z,bn.z,an[2][2]); an[2][3]=fmaf(a.z,bn.w,an[2][3]);
        an[3][0]=fmaf(a.w,bn.x,an[3][0]); an[3][1]=fmaf(a.w,bn.y,an[3][1]);
        an[3][2]=fmaf(a.w,bn.z,an[3][2]); an[3][3]=fmaf(a.w,bn.w,an[3][3]);
        ag2[0][0]=fmaf(a.x,bg.x,ag2[0][0]); ag2[0][1]=fmaf(a.x,bg.y,ag2[0][1]);
        ag2[0][2]=fmaf(a.x,bg.z,ag2[0][2]); ag2[0][3]=fmaf(a.x,bg.w,ag2[0][3]);
        ag2[1][0]=fmaf(a.y,bg.x,ag2[1][0]); ag2[1][1]=fmaf(a.y,bg.y,ag2[1][1]);
        ag2[1][2]=fmaf(a.y,bg.z,ag2[1][2]); ag2[1][3]=fmaf(a.y,bg.w,ag2[1][3]);
        ag2[2][0]=fmaf(a.z,bg.x,ag2[2][0]); ag2[2][1]=fmaf(a.z,bg.y,ag2[2][1]);
        ag2[2][2]=fmaf(a.z,bg.z,ag2[2][2]); ag2[2][3]=fmaf(a.z,bg.w,ag2[2][3]);
        ag2[3][0]=fmaf(a.w,bg.x,ag2[3][0]); ag2[3][1]=fmaf(a.w,bg.y,ag2[3][1]);
        ag2[3][2]=fmaf(a.w,bg.z,ag2[3][2]); ag2[3][3]=fmaf(a.w,bg.w,ag2[3][3]);
      }
      __syncthreads();
    }
    #pragma unroll
    for (int i=0;i<4;i++){
      const int rl = (tm<<2) + i;
      const int r  = row0 + rl;
      #pragma unroll
      for (int j=0;j<4;j++){
        const int c = col0 + (tn<<2) + j;
        const float nl = an[i][j] + hwb[c];
        const float gt = ag2[i][j] + hwb[512 + c];
        const float hv = At[c][rl];
        const float gv = sigf(gt);
        h[(size_t)r*512 + c] = gv*hv + (1.f-gv)*fmaxf(nl, 0.f);
      }
    }
  }
}

__global__ __launch_bounds__(256) void gold_kernel(
    const int* __restrict__ labels, const int* __restrict__ maskp,
    const float* __restrict__ emitp, const float* __restrict__ trans, double* __restrict__ gold) {
  const int b = blockIdx.x; const int tid = threadIdx.x;
  double acc = 0.0; int len = 0;
  for (int t = tid; t < S_; t += 256) {
    int mk = maskp[b*S_ + t];
    len += mk;
    if (mk) {
      int lab  = labels[b*S_ + t];
      int prev = (t==0) ? START_ : labels[b*S_ + t - 1];
      acc += (double)trans[prev*T_ + lab] + (double)emitp[((size_t)b*S_ + t)*T_ + lab];
    }
  }
  __shared__ double sacc[256]; __shared__ int slen[256];
  sacc[tid]=acc; slen[tid]=len; __syncthreads();
  for (int s=128; s>0; s>>=1){ if (tid<s){ sacc[tid]+=sacc[tid+s]; slen[tid]+=slen[tid+s]; } __syncthreads(); }
  if (tid==0){
    int L = slen[0];
    int last = labels[b*S_ + L - 1];
    gold[b] = sacc[0] + (double)trans[last*T_ + STOP_];
  }
}

// Fused CRF-forward (role 0) + Viterbi (role 1). One wave per (batch, role).
__global__ __launch_bounds__(64) void crf_vit_kernel(
    const float* __restrict__ emitp, const float* __restrict__ trans,
    const int* __restrict__ maskp, double* __restrict__ fwd, float* __restrict__ out_tags) {
  const int b = blockIdx.x;
  const int role = blockIdx.y;
  const int lane = threadIdx.x;
  const int k = lane & 31, p = lane >> 5;
  const int kk = (k < T_) ? k : 0;

  if (role == 0) {
    __shared__ float trs[T_*T_];
    __shared__ double al[T_];
    for (int i = lane; i < T_*T_; i += 64) trs[i] = trans[i];
    __syncthreads();
    if (lane < T_) al[lane] = (double)emitp[(size_t)b*S_*T_ + lane] + (double)trs[START_*T_ + lane];
    __syncthreads();
    float ce = emitp[((size_t)b*S_ + 1)*T_ + kk];
    int   cm = maskp[b*S_ + 1];
    for (int t = 1; t < S_; ++t) {
      float ne = 0.f; int nm = 0;
      if (t+1 < S_) { ne = emitp[((size_t)b*S_ + t + 1)*T_ + kk]; nm = maskp[b*S_ + t + 1]; }
      double tj[11];
      #pragma unroll
      for (int u = 0; u < 11; ++u) {
        const int j = p*11 + u;
        tj[u] = al[j] + (double)trs[j*T_ + kk];
      }
      double m = tj[0];
      #pragma unroll
      for (int u = 1; u < 11; ++u) m = fmax(m, tj[u]);
      m = fmax(m, __shfl_xor(m, 32));
      float s = 0.f;
      #pragma unroll
      for (int u = 0; u < 11; ++u) s += __expf((float)(tj[u] - m));
      s += __shfl_xor(s, 32);
      const double nv = m + (double)__logf(s) + (double)ce;
      __syncthreads();
      if (cm && p == 0 && k < T_) al[k] = nv;
      __syncthreads();
      ce = ne; cm = nm;
    }
    if (lane == 0) {
      double mx = -1e300;
      for (int j = 0; j < T_; ++j) mx = fmax(mx, al[j] + (double)trs[j*T_ + STOP_]);
      double s = 0.0;
      for (int j = 0; j < T_; ++j) s += exp(al[j] + (double)trs[j*T_ + STOP_] - mx);
      fwd[b] = mx + log(s);
    }
  } else {
    __shared__ double tr64[T_*T_];
    __shared__ double dl[T_];
    __shared__ unsigned char bp[S_][T_];
    __shared__ int msk[S_];
    for (int i = lane; i < T_*T_; i += 64) tr64[i] = (double)trans[i];
    __syncthreads();
    if (lane < T_) dl[lane] = (double)emitp[(size_t)b*S_*T_ + lane] + tr64[START_*T_ + lane];
    if (lane == 0) msk[0] = maskp[b*S_];
    __syncthreads();
    float ce = emitp[((size_t)b*S_ + 1)*T_ + kk];
    int   cm = maskp[b*S_ + 1];
    for (int t = 1; t < S_; ++t) {
      float ne = 0.f; int nm = 0;
      if (t+1 < S_) { ne = emitp[((size_t)b*S_ + t + 1)*T_ + kk]; nm = maskp[b*S_ + t + 1]; }
      double best = dl[p*11] + tr64[(p*11)*T_ + kk];
      int arg = p*11;
      #pragma unroll
      for (int u = 1; u < 11; ++u) {
        const int j = p*11 + u;
        const double sc = dl[j] + tr64[j*T_ + kk];
        if (sc > best) { best = sc; arg = j; }
      }
      const double ob = __shfl_xor(best, 32);
      const int    oa = __shfl_xor(arg, 32);
      if (p == 0 && ob > best) { best = ob; arg = oa; }
      __syncthreads();
      if (p == 0 && k < T_) {
        if (cm) { dl[k] = best + (double)ce; bp[t][k] = (unsigned char)arg; }
        else    { bp[t][k] = (unsigned char)k; }
      }
      if (lane == 0) msk[t] = cm;
      __syncthreads();
      ce = ne; cm = nm;
    }
    if (lane == 0) {
      double bb = dl[0] + tr64[STOP_]; int cur = 0;
      for (int j = 1; j < T_; ++j) { const double sc = dl[j] + tr64[j*T_ + STOP_]; if (sc > bb) { bb = sc; cur = j; } }
      for (int t = S_-1; ; --t) {
        out_tags[b*S_ + t] = (float)(cur * msk[t]);
        if (t == 0) break;
        cur = bp[t][cur];
      }
    }
  }
}

__global__ void finalize_kernel(const double* __restrict__ fwd, const double* __restrict__ gold, float* __restrict__ out){
  if (threadIdx.x == 0 && blockIdx.x == 0) {
    double s = 0.0, g = 0.0;
    for (int b = 0; b < B_; ++b) { s += fwd[b]; g += gold[b]; }
    out[0] = (float)((s - g) / (double)B_);
  }
}

extern "C" void kernel_launch(void* const* d_in, const int* in_sizes, int n_in,
                              void* d_out, int out_size, void* d_ws, size_t ws_size,
                              hipStream_t stream) {
  const int*   word   = (const int*)d_in[0];
  const int*   maskp  = (const int*)d_in[1];
  const int*   labels = (const int*)d_in[2];
  const float* emb    = (const float*)d_in[3];
  const float* w_ih_f = (const float*)d_in[4];
  const float* w_hh_f = (const float*)d_in[5];
  const float* b_f    = (const float*)d_in[6];
  const float* w_ih_b = (const float*)d_in[7];
  const float* w_hh_b = (const float*)d_in[8];
  const float* b_b    = (const float*)d_in[9];
  const float* hw_W   = (const float*)d_in[10];
  const float* hw_b   = (const float*)d_in[11];
  const float* out_W  = (const float*)d_in[12];
  const float* out_b  = (const float*)d_in[13];
  const float* trans  = (const float*)d_in[14];
  float* out = (float*)d_out;

  // workspace layout (~88 MB)
  float* h_bi  = (float*)d_ws;                          // [32768,512] -> h2 in place
  float* buf0  = h_bi + 16777216ULL;                    // [2,1024,1024] gates ping
  float* buf1  = buf0 + 2097152ULL;                     // [2,1024,1024] gates pong
  __half* wTf16 = (__half*)(buf1 + 2097152ULL);         // [256,1024] fp16
  __half* wTb16 = wTf16 + 262144ULL;                    // [256,1024] fp16
  float* emitp = (float*)(wTb16 + 262144ULL);           // [32768,22]
  float* stH   = emitp + 720896ULL;                     // [2,64,256]
  float* stC   = stH + 32768ULL;                        // [2,64,256]
  double* fwdp = (double*)(stC + 32768ULL);             // [64]
  double* goldp = fwdp + 64;                            // [64]

  wtr_kernel<<<1024, 256, 0, stream>>>(w_hh_f, wTf16);
  wtr_kernel<<<1024, 256, 0, stream>>>(w_hh_b, wTb16);

  // chunk 0 gates -> buf0
  gemm_tiled<<<dim3(CROWS/64, 16), 256, 0, stream>>>(
      nullptr, word, maskp, emb, w_ih_f, b_f, buf0, E_, G4_, 1, 0, C_);
  gemm_tiled<<<dim3(CROWS/64, 16), 256, 0, stream>>>(
      nullptr, word, maskp, emb, w_ih_b, b_b, buf0 + (size_t)CROWS*G4_, E_, G4_, 1, S_ - C_, C_);

  // fused recurrence + next-chunk projection
  for (int i = 0; i < NCH; ++i) {
    const int t0f = i * C_;
    const int t0b = S_ - (i + 1) * C_;
    const int n0f = (i + 1) * C_;
    const int n0b = S_ - (i + 2) * C_;
    float* gcur = (i & 1) ? buf1 : buf0;
    float* gnext = (i & 1) ? buf0 : buf1;
    const int nblocks = (i < NCH - 1) ? (64 + 512) : 64;
    lstm_fused<<<nblocks, 256, 0, stream>>>(
        gcur, gnext, word, maskp, emb, w_ih_f, b_f, w_ih_b, b_b,
        wTf16, wTb16, h_bi, stH, stC, t0f, t0b, n0f, n0b, (i == 0) ? 1 : 0);
  }

  // fused highway (in place on h_bi)
  gemm_hw<<<512, 256, 0, stream>>>(h_bi, hw_W, hw_b);

  // emissions
  gemm_tiled<<<dim3(M_/64, 1), 256, 0, stream>>>(
      h_bi, nullptr, nullptr, nullptr, out_W, out_b, emitp, 2*H_, T_, 0, 0, C_);

  // CRF
  gold_kernel<<<64, 256, 0, stream>>>(labels, maskp, emitp, trans, goldp);
  crf_vit_kernel<<<dim3(64, 2), 64, 0, stream>>>(emitp, trans, maskp, fwdp, out + 1);
  finalize_kernel<<<1, 64, 0, stream>>>(fwdp, goldp, out);
}

// Round 5
// 5824.947 us; speedup vs baseline: 1.2039x; 1.2039x over previous
//
#include <hip/hip_runtime.h>
#include <math.h>

#define B_  64
#define S_  512
#define E_  300
#define H_  256
#define G4_ 1024
#define T_  22
#define M_  (B_*S_)
#define C_  16              // LSTM time chunk
#define NCH (S_/C_)         // 32 chunks
#define CROWS (B_*C_)       // 1024 rows per chunk per dir
#define RCH 4096            // highway row chunk
#define START_ (T_-2)
#define STOP_  (T_-1)

__device__ __forceinline__ float sigf(float x){ return 1.f/(1.f+expf(-x)); }

// w_hh [1024,256] -> wT [256][1024] with wT[k][4*j+g] = w_hh[g*256+j][k]
__global__ __launch_bounds__(256) void wtr_kernel(const float* __restrict__ whh, float* __restrict__ wT){
  int tid = blockIdx.x*256 + threadIdx.x;
  if (tid >= H_*G4_) return;
  int k = tid >> 10;
  int r = tid & 1023;
  int j = r >> 2, gi = r & 3;
  wT[tid] = whh[(size_t)(gi*H_ + j)*H_ + k];
}

struct __align__(16) TileSmem {
  float As[16][68];
  float Bs[16][68];
  int   widx[64];
  float wmsk[64];
};

// 64x64 tile GEMM body on 256 logical threads (tid param, NOT threadIdx).
// gather mode: local row r -> word/mask flat index (r/chunkC)*S_ + t0 + (r%chunkC)
__device__ __forceinline__ void gemm_tile_body(
    TileSmem& sm, int tid,
    const float* __restrict__ A,
    const int* __restrict__ word, const int* __restrict__ maskp, const float* __restrict__ emb,
    const float* __restrict__ W, const float* __restrict__ bias,
    float* __restrict__ C, int K, int N, int gather, int t0, int chunkC,
    int row0, int col0) {
  const int tn = tid & 15, tm = tid >> 4;
  if (gather) {
    if (tid < 64) {
      int r  = row0 + tid;
      int b  = r / chunkC;
      int tl = r % chunkC;
      int wr = b*S_ + t0 + tl;
      sm.widx[tid] = word[wr];
      sm.wmsk[tid] = (float)maskp[wr];
    }
    __syncthreads();
  }
  float acc[4][4];
  #pragma unroll
  for (int i=0;i<4;i++)
    #pragma unroll
    for (int j=0;j<4;j++) acc[i][j]=0.f;

  for (int k0 = 0; k0 < K; k0 += 16) {
    #pragma unroll
    for (int i = 0; i < 4; ++i) {
      const int li = tid + (i<<8);
      const int m  = li >> 4, kk = li & 15;
      const int kg = k0 + kk;
      float av = 0.f;
      if (kg < K) {
        if (gather) av = emb[(size_t)sm.widx[m]*K + kg] * sm.wmsk[m];
        else        av = A[(size_t)(row0+m)*K + kg];
      }
      sm.As[kk][m] = av;
      const int nc = col0 + m;
      sm.Bs[kk][m] = (kg < K && nc < N) ? W[(size_t)nc*K + kg] : 0.f;
    }
    __syncthreads();
    #pragma unroll
    for (int kk = 0; kk < 16; ++kk) {
      const float4 a = *(const float4*)&sm.As[kk][tm<<2];
      const float4 b = *(const float4*)&sm.Bs[kk][tn<<2];
      acc[0][0]=fmaf(a.x,b.x,acc[0][0]); acc[0][1]=fmaf(a.x,b.y,acc[0][1]);
      acc[0][2]=fmaf(a.x,b.z,acc[0][2]); acc[0][3]=fmaf(a.x,b.w,acc[0][3]);
      acc[1][0]=fmaf(a.y,b.x,acc[1][0]); acc[1][1]=fmaf(a.y,b.y,acc[1][1]);
      acc[1][2]=fmaf(a.y,b.z,acc[1][2]); acc[1][3]=fmaf(a.y,b.w,acc[1][3]);
      acc[2][0]=fmaf(a.z,b.x,acc[2][0]); acc[2][1]=fmaf(a.z,b.y,acc[2][1]);
      acc[2][2]=fmaf(a.z,b.z,acc[2][2]); acc[2][3]=fmaf(a.z,b.w,acc[2][3]);
      acc[3][0]=fmaf(a.w,b.x,acc[3][0]); acc[3][1]=fmaf(a.w,b.y,acc[3][1]);
      acc[3][2]=fmaf(a.w,b.z,acc[3][2]); acc[3][3]=fmaf(a.w,b.w,acc[3][3]);
    }
    __syncthreads();
  }
  #pragma unroll
  for (int i=0;i<4;i++){
    const int r = row0 + (tm<<2) + i;
    #pragma unroll
    for (int j=0;j<4;j++){
      const int c = col0 + (tn<<2) + j;
      if (c < N) C[(size_t)r*N + c] = acc[i][j] + bias[c];
    }
  }
}

__global__ __launch_bounds__(256) void gemm_tiled(
    const float* __restrict__ A,
    const int* __restrict__ word, const int* __restrict__ maskp, const float* __restrict__ emb,
    const float* __restrict__ W, const float* __restrict__ bias,
    float* __restrict__ C, int K, int N, int gather, int t0, int chunkC) {
  __shared__ TileSmem sm;
  gemm_tile_body(sm, threadIdx.x, A, word, maskp, emb, W, bias, C, K, N,
                 gather, t0, chunkC, blockIdx.x << 6, blockIdx.y << 6);
}

// Fused launch, 512 threads/block.
// blocks [0,64): recurrence, one block = 2 batch x 1 dir; threads (col, kh) k-split.
// blocks [64,64+256): next-chunk projection, 2 tiles per block (one per 256-thread half).
__global__ __launch_bounds__(512) void lstm_fused(
    const float* __restrict__ gcur, float* __restrict__ gnext,
    const int* __restrict__ word, const int* __restrict__ maskp, const float* __restrict__ emb,
    const float* __restrict__ w_ih_f, const float* __restrict__ b_f,
    const float* __restrict__ w_ih_b, const float* __restrict__ b_b,
    const float* __restrict__ wTf, const float* __restrict__ wTb,
    float* __restrict__ h_bi, float* __restrict__ stH, float* __restrict__ stC,
    int t0f, int t0b, int n0f, int n0b, int first) {
  const int bid = blockIdx.x;
  const int tid = threadIdx.x;
  if (bid >= 64) {
    __shared__ TileSmem ts[2];
    const int half = tid >> 8;
    const int t256 = tid & 255;
    const int tile = (bid - 64) * 2 + half;   // 0..511
    const int dir  = tile >> 8;
    const int tt   = tile & 255;
    const int rowt = tt & 15, colt = tt >> 4;
    const float* W  = dir ? w_ih_b : w_ih_f;
    const float* bs = dir ? b_b : b_f;
    float* Cout = gnext + (size_t)dir * CROWS * G4_;
    const int t0 = dir ? n0b : n0f;
    gemm_tile_body(ts[half], t256, nullptr, word, maskp, emb, W, bs, Cout,
                   E_, G4_, 1, t0, C_, rowt << 6, colt << 6);
    return;
  }
  // ---- recurrence role: 512 threads, k-split ----
  const int dir = bid & 1;
  const float* __restrict__ g  = gcur + (size_t)dir * CROWS * G4_;
  const float* __restrict__ wT = dir ? wTb : wTf;
  const int b0 = (bid >> 1) * 2;
  const int hoff = dir ? H_ : 0;
  const int col = tid & 255;     // hidden index j (owns gates 4j..4j+3)
  const int kh  = tid >> 8;      // k-half
  __shared__ float hp[H_][2];
  __shared__ float psum[256][9]; // padded: stride 9 -> conflict-free
  float c0 = 0.f, c1 = 0.f;
  if (kh == 0) {
    if (first) {
      hp[col][0] = 0.f; hp[col][1] = 0.f;
    } else {
      hp[col][0] = stH[((size_t)(dir*B_ + b0))*H_ + col];
      hp[col][1] = stH[((size_t)(dir*B_ + b0 + 1))*H_ + col];
      c0 = stC[((size_t)(dir*B_ + b0))*H_ + col];
      c1 = stC[((size_t)(dir*B_ + b0 + 1))*H_ + col];
    }
  }
  __syncthreads();
  const int kbase = kh << 7;
  for (int sl = 0; sl < C_; ++sl) {
    const int t  = dir ? (t0b + C_ - 1 - sl) : (t0f + sl);
    const int tl = dir ? (C_ - 1 - sl) : sl;
    float a0=0.f,a1=0.f,a2=0.f,a3=0.f,a4=0.f,a5=0.f,a6=0.f,a7=0.f;
    #pragma unroll 8
    for (int ku = 0; ku < 128; ++ku) {
      const int k = kbase + ku;
      const float4 w = *(const float4*)(wT + ((k<<10) + (col<<2)));
      const float h0 = hp[k][0], h1 = hp[k][1];
      a0 = fmaf(w.x, h0, a0); a1 = fmaf(w.y, h0, a1);
      a2 = fmaf(w.z, h0, a2); a3 = fmaf(w.w, h0, a3);
      a4 = fmaf(w.x, h1, a4); a5 = fmaf(w.y, h1, a5);
      a6 = fmaf(w.z, h1, a6); a7 = fmaf(w.w, h1, a7);
    }
    if (kh == 1) {
      psum[col][0]=a0; psum[col][1]=a1; psum[col][2]=a2; psum[col][3]=a3;
      psum[col][4]=a4; psum[col][5]=a5; psum[col][6]=a6; psum[col][7]=a7;
    }
    __syncthreads();
    if (kh == 0) {
      const float ai0 = a0 + psum[col][0];
      const float af0 = a1 + psum[col][1];
      const float ag0 = a2 + psum[col][2];
      const float ao0 = a3 + psum[col][3];
      const float ai1 = a4 + psum[col][4];
      const float af1 = a5 + psum[col][5];
      const float ag1 = a6 + psum[col][6];
      const float ao1 = a7 + psum[col][7];
      const size_t r0 = ((size_t)(b0*C_ + tl)) << 10;
      const size_t r1 = ((size_t)((b0+1)*C_ + tl)) << 10;
      const float i0 = sigf(g[r0 + col] + ai0);
      const float f0 = sigf(g[r0 + H_ + col] + af0);
      const float z0 = tanhf(g[r0 + 2*H_ + col] + ag0);
      const float o0 = sigf(g[r0 + 3*H_ + col] + ao0);
      c0 = f0*c0 + i0*z0;
      const float hn0 = o0 * tanhf(c0);
      const float i1 = sigf(g[r1 + col] + ai1);
      const float f1 = sigf(g[r1 + H_ + col] + af1);
      const float z1 = tanhf(g[r1 + 2*H_ + col] + ag1);
      const float o1 = sigf(g[r1 + 3*H_ + col] + ao1);
      c1 = f1*c1 + i1*z1;
      const float hn1 = o1 * tanhf(c1);
      hp[col][0] = hn0; hp[col][1] = hn1;
      h_bi[((size_t)(b0*S_ + t))*(2*H_) + hoff + col] = hn0;
      h_bi[((size_t)((b0+1)*S_ + t))*(2*H_) + hoff + col] = hn1;
    }
    __syncthreads();
  }
  if (kh == 0) {
    stH[((size_t)(dir*B_ + b0))*H_ + col]     = hp[col][0];
    stH[((size_t)(dir*B_ + b0 + 1))*H_ + col] = hp[col][1];
    stC[((size_t)(dir*B_ + b0))*H_ + col]     = c0;
    stC[((size_t)(dir*B_ + b0 + 1))*H_ + col] = c1;
  }
}

// in-place highway over one row chunk
__global__ __launch_bounds__(256) void highway_kernel(
    const float* __restrict__ proj, float* __restrict__ h) {
  int idx = blockIdx.x*256 + threadIdx.x;
  int m = idx >> 9, j = idx & 511;
  float nl = proj[((size_t)m<<10) + j];
  float gt = proj[((size_t)m<<10) + 512 + j];
  float hv = h[idx];
  float gv = sigf(gt);
  h[idx] = gv*hv + (1.f-gv)*fmaxf(nl, 0.f);
}

__global__ __launch_bounds__(256) void gold_kernel(
    const int* __restrict__ labels, const int* __restrict__ maskp,
    const float* __restrict__ emitp, const float* __restrict__ trans, double* __restrict__ gold) {
  const int b = blockIdx.x; const int tid = threadIdx.x;
  double acc = 0.0; int len = 0;
  for (int t = tid; t < S_; t += 256) {
    int mk = maskp[b*S_ + t];
    len += mk;
    if (mk) {
      int lab  = labels[b*S_ + t];
      int prev = (t==0) ? START_ : labels[b*S_ + t - 1];
      acc += (double)trans[prev*T_ + lab] + (double)emitp[((size_t)b*S_ + t)*T_ + lab];
    }
  }
  __shared__ double sacc[256]; __shared__ int slen[256];
  sacc[tid]=acc; slen[tid]=len; __syncthreads();
  for (int s=128; s>0; s>>=1){ if (tid<s){ sacc[tid]+=sacc[tid+s]; slen[tid]+=slen[tid+s]; } __syncthreads(); }
  if (tid==0){
    int L = slen[0];
    int last = labels[b*S_ + L - 1];
    gold[b] = sacc[0] + (double)trans[last*T_ + STOP_];
  }
}

// Fused CRF-forward (role 0) + Viterbi (role 1). One wave per (batch, role).
__global__ __launch_bounds__(64) void crf_vit_kernel(
    const float* __restrict__ emitp, const float* __restrict__ trans,
    const int* __restrict__ maskp, double* __restrict__ fwd, float* __restrict__ out_tags) {
  const int b = blockIdx.x;
  const int role = blockIdx.y;
  const int lane = threadIdx.x;
  const int k = lane & 31, p = lane >> 5;
  const int kk = (k < T_) ? k : 0;

  if (role == 0) {
    __shared__ float trs[T_*T_];
    __shared__ double al[T_];
    for (int i = lane; i < T_*T_; i += 64) trs[i] = trans[i];
    __syncthreads();
    if (lane < T_) al[lane] = (double)emitp[(size_t)b*S_*T_ + lane] + (double)trs[START_*T_ + lane];
    __syncthreads();
    float ce = emitp[((size_t)b*S_ + 1)*T_ + kk];
    int   cm = maskp[b*S_ + 1];
    for (int t = 1; t < S_; ++t) {
      float ne = 0.f; int nm = 0;
      if (t+1 < S_) { ne = emitp[((size_t)b*S_ + t + 1)*T_ + kk]; nm = maskp[b*S_ + t + 1]; }
      double tj[11];
      #pragma unroll
      for (int u = 0; u < 11; ++u) {
        const int j = p*11 + u;
        tj[u] = al[j] + (double)trs[j*T_ + kk];
      }
      double m = tj[0];
      #pragma unroll
      for (int u = 1; u < 11; ++u) m = fmax(m, tj[u]);
      m = fmax(m, __shfl_xor(m, 32));
      float s = 0.f;
      #pragma unroll
      for (int u = 0; u < 11; ++u) s += __expf((float)(tj[u] - m));
      s += __shfl_xor(s, 32);
      const double nv = m + (double)__logf(s) + (double)ce;
      __syncthreads();
      if (cm && p == 0 && k < T_) al[k] = nv;
      __syncthreads();
      ce = ne; cm = nm;
    }
    if (lane == 0) {
      double mx = -1e300;
      for (int j = 0; j < T_; ++j) mx = fmax(mx, al[j] + (double)trs[j*T_ + STOP_]);
      double s = 0.0;
      for (int j = 0; j < T_; ++j) s += exp(al[j] + (double)trs[j*T_ + STOP_] - mx);
      fwd[b] = mx + log(s);
    }
  } else {
    __shared__ double tr64[T_*T_];
    __shared__ double dl[T_];
    __shared__ unsigned char bp[S_][T_];
    __shared__ int msk[S_];
    for (int i = lane; i < T_*T_; i += 64) tr64[i] = (double)trans[i];
    __syncthreads();
    if (lane < T_) dl[lane] = (double)emitp[(size_t)b*S_*T_ + lane] + tr64[START_*T_ + lane];
    if (lane == 0) msk[0] = maskp[b*S_];
    __syncthreads();
    float ce = emitp[((size_t)b*S_ + 1)*T_ + kk];
    int   cm = maskp[b*S_ + 1];
    for (int t = 1; t < S_; ++t) {
      float ne = 0.f; int nm = 0;
      if (t+1 < S_) { ne = emitp[((size_t)b*S_ + t + 1)*T_ + kk]; nm = maskp[b*S_ + t + 1]; }
      double best = dl[p*11] + tr64[(p*11)*T_ + kk];
      int arg = p*11;
      #pragma unroll
      for (int u = 1; u < 11; ++u) {
        const int j = p*11 + u;
        const double sc = dl[j] + tr64[j*T_ + kk];
        if (sc > best) { best = sc; arg = j; }
      }
      const double ob = __shfl_xor(best, 32);
      const int    oa = __shfl_xor(arg, 32);
      if (p == 0 && ob > best) { best = ob; arg = oa; }
      __syncthreads();
      if (p == 0 && k < T_) {
        if (cm) { dl[k] = best + (double)ce; bp[t][k] = (unsigned char)arg; }
        else    { bp[t][k] = (unsigned char)k; }
      }
      if (lane == 0) msk[t] = cm;
      __syncthreads();
      ce = ne; cm = nm;
    }
    if (lane == 0) {
      double bb = dl[0] + tr64[STOP_]; int cur = 0;
      for (int j = 1; j < T_; ++j) { const double sc = dl[j] + tr64[j*T_ + STOP_]; if (sc > bb) { bb = sc; cur = j; } }
      for (int t = S_-1; ; --t) {
        out_tags[b*S_ + t] = (float)(cur * msk[t]);
        if (t == 0) break;
        cur = bp[t][cur];
      }
    }
  }
}

__global__ void finalize_kernel(const double* __restrict__ fwd, const double* __restrict__ gold, float* __restrict__ out){
  if (threadIdx.x == 0 && blockIdx.x == 0) {
    double s = 0.0, g = 0.0;
    for (int b = 0; b < B_; ++b) { s += fwd[b]; g += gold[b]; }
    out[0] = (float)((s - g) / (double)B_);
  }
}

extern "C" void kernel_launch(void* const* d_in, const int* in_sizes, int n_in,
                              void* d_out, int out_size, void* d_ws, size_t ws_size,
                              hipStream_t stream) {
  const int*   word   = (const int*)d_in[0];
  const int*   maskp  = (const int*)d_in[1];
  const int*   labels = (const int*)d_in[2];
  const float* emb    = (const float*)d_in[3];
  const float* w_ih_f = (const float*)d_in[4];
  const float* w_hh_f = (const float*)d_in[5];
  const float* b_f    = (const float*)d_in[6];
  const float* w_ih_b = (const float*)d_in[7];
  const float* w_hh_b = (const float*)d_in[8];
  const float* b_b    = (const float*)d_in[9];
  const float* hw_W   = (const float*)d_in[10];
  const float* hw_b   = (const float*)d_in[11];
  const float* out_W  = (const float*)d_in[12];
  const float* out_b  = (const float*)d_in[13];
  const float* trans  = (const float*)d_in[14];
  float* out = (float*)d_out;

  // workspace layout (~89 MB, known good)
  float* h_bi  = (float*)d_ws;                          // [32768,512] -> h2 in place
  float* buf0  = h_bi + 16777216ULL;                    // [2,1024,1024] gates ping
  float* buf1  = buf0 + 2097152ULL;                     // [2,1024,1024] gates pong
  float* wTf   = buf1 + 2097152ULL;                     // [256,1024]
  float* wTb   = wTf + 262144ULL;                       // [256,1024]
  float* emitp = wTb + 262144ULL;                       // [32768,22]
  float* stH   = emitp + 720896ULL;                     // [2,64,256]
  float* stC   = stH + 32768ULL;                        // [2,64,256]
  double* fwdp = (double*)(stC + 32768ULL);             // [64]
  double* goldp = fwdp + 64;                            // [64]

  wtr_kernel<<<1024, 256, 0, stream>>>(w_hh_f, wTf);
  wtr_kernel<<<1024, 256, 0, stream>>>(w_hh_b, wTb);

  // chunk 0 gates -> buf0
  gemm_tiled<<<dim3(CROWS/64, 16), 256, 0, stream>>>(
      nullptr, word, maskp, emb, w_ih_f, b_f, buf0, E_, G4_, 1, 0, C_);
  gemm_tiled<<<dim3(CROWS/64, 16), 256, 0, stream>>>(
      nullptr, word, maskp, emb, w_ih_b, b_b, buf0 + (size_t)CROWS*G4_, E_, G4_, 1, S_ - C_, C_);

  // fused recurrence (k-split, 512 thr) + next-chunk projection (2 tiles/block)
  for (int i = 0; i < NCH; ++i) {
    const int t0f = i * C_;
    const int t0b = S_ - (i + 1) * C_;
    const int n0f = (i + 1) * C_;
    const int n0b = S_ - (i + 2) * C_;
    float* gcur = (i & 1) ? buf1 : buf0;
    float* gnext = (i & 1) ? buf0 : buf1;
    const int nblocks = (i < NCH - 1) ? (64 + 256) : 64;
    lstm_fused<<<nblocks, 512, 0, stream>>>(
        gcur, gnext, word, maskp, emb, w_ih_f, b_f, w_ih_b, b_b,
        wTf, wTb, h_bi, stH, stC, t0f, t0b, n0f, n0b, (i == 0) ? 1 : 0);
  }

  // highway in row chunks (proj into buf0), h2 in place
  for (int rc = 0; rc < M_ / RCH; ++rc) {
    float* Ach = h_bi + (size_t)rc * RCH * 512;
    gemm_tiled<<<dim3(RCH/64, 16), 256, 0, stream>>>(
        Ach, nullptr, nullptr, nullptr, hw_W, hw_b, buf0, 2*H_, G4_, 0, 0, C_);
    highway_kernel<<<(RCH*512)/256, 256, 0, stream>>>(buf0, Ach);
  }

  // emissions
  gemm_tiled<<<dim3(M_/64, 1), 256, 0, stream>>>(
      h_bi, nullptr, nullptr, nullptr, out_W, out_b, emitp, 2*H_, T_, 0, 0, C_);

  // CRF
  gold_kernel<<<64, 256, 0, stream>>>(labels, maskp, emitp, trans, goldp);
  crf_vit_kernel<<<dim3(64, 2), 64, 0, stream>>>(emitp, trans, maskp, fwdp, out + 1);
  finalize_kernel<<<1, 64, 0, stream>>>(fwdp, goldp, out);
}